// Round 22
// baseline (384.865 us; speedup 1.0000x reference)
//
#include <hip/hip_runtime.h>

#define B_ 4
#define C_ 64
#define H_ 256
#define W_ 256
#define HW_ (H_*W_)
#define MID_ 12
#define NPB_ 256   // gap partial slots per image (= one per row)

typedef _Float16 h4 __attribute__((ext_vector_type(4)));

__device__ __forceinline__ float wave_reduce64(float v) {
#pragma unroll
    for (int off = 32; off; off >>= 1) v += __shfl_xor(v, off, 64);
    return v;
}

// ---------------- prep: read in once -> s (pixel-major) + gap partials ----------------
// block = 1 row, 4 waves x 16 channels; lane = 4 px. grid (H, B).
// Tail: ALL 256 threads each fnorm one pixel (parallel, was wave0-only).
template<bool HALF>
__global__ __launch_bounds__(256, 4) void prep_kernel(const void* __restrict__ xin,
    const float* __restrict__ sw, const float* __restrict__ sb,
    const float* __restrict__ sstd, float* __restrict__ sarr, float* __restrict__ gp) {
    const int lane = threadIdx.x & 63, wv = threadIdx.x >> 6;
    const int row = blockIdx.x;
    const int b = blockIdx.y;
    const int c0 = wv * 16;
    const int pix = row * W_ + lane * 4;
    __shared__ float stl[4][9][64][4];   // [wave][tap][lane][px-in-lane]

    float4 st[9];
#pragma unroll
    for (int t = 0; t < 9; ++t) st[t] = make_float4(0, 0, 0, 0);

    const size_t base = (size_t)b * C_ * HW_ + pix;
    const float* xbF = (const float*)xin + base;
    const _Float16* xbH = (const _Float16*)xin + base;

#define LOAD4(DST, CC) do {                                                   \
        if constexpr (HALF) {                                                 \
            h4 v_ = *(const h4*)(xbH + (size_t)(CC) * HW_);                   \
            DST = make_float4((float)v_[0], (float)v_[1],                     \
                              (float)v_[2], (float)v_[3]);                    \
        } else {                                                              \
            DST = *(const float4*)(xbF + (size_t)(CC) * HW_);                 \
        }                                                                     \
    } while (0)

#define PREP_COMP(BUF, CC) do {                                               \
        _Pragma("unroll")                                                     \
        for (int i_ = 0; i_ < 4; ++i_) {                                      \
            const int c_ = (CC) + i_;                                         \
            float4 v_ = BUF[i_];                                              \
            _Pragma("unroll")                                                 \
            for (int t_ = 0; t_ < 9; ++t_) {                                  \
                const float wt_ = sw[t_ * C_ + c_];                           \
                st[t_].x = fmaf(v_.x, wt_, st[t_].x);                         \
                st[t_].y = fmaf(v_.y, wt_, st[t_].y);                         \
                st[t_].z = fmaf(v_.z, wt_, st[t_].z);                         \
                st[t_].w = fmaf(v_.w, wt_, st[t_].w);                         \
            }                                                                 \
            float g_ = wave_reduce64(((v_.x + v_.y) + (v_.z + v_.w)));        \
            if (lane == 0) gp[((size_t)b * C_ + c_) * NPB_ + blockIdx.x] = g_; \
        }                                                                     \
    } while (0)

    float4 vA[4], vB[4];
#pragma unroll
    for (int i = 0; i < 4; ++i) LOAD4(vA[i], c0 + i);
#pragma unroll
    for (int k = 0; k < 16; k += 8) {
#pragma unroll
        for (int i = 0; i < 4; ++i) LOAD4(vB[i], c0 + k + 4 + i);
        PREP_COMP(vA, c0 + k);
        if (k + 8 < 16) {
#pragma unroll
            for (int i = 0; i < 4; ++i) LOAD4(vA[i], c0 + k + 8 + i);
        }
        PREP_COMP(vB, c0 + k + 4);
    }
#undef LOAD4
#undef PREP_COMP

#pragma unroll
    for (int t = 0; t < 9; ++t) *(float4*)&stl[wv][t][lane][0] = st[t];
    __syncthreads();

    // parallel tail: each thread fnorms ONE pixel of this row
    {
        const int pxl = threadIdx.x;          // 0..255 local col
        const int lf = pxl >> 2, j = pxl & 3;
        float v9[9];
        float mean = 0.f;
#pragma unroll
        for (int t = 0; t < 9; ++t) {
            float s = sb[t] + stl[0][t][lf][j] + stl[1][t][lf][j]
                            + stl[2][t][lf][j] + stl[3][t][lf][j];
            v9[t] = s;
            mean += s;
        }
        mean *= (1.f / 9.f);
        float var = 0.f;
#pragma unroll
        for (int t = 0; t < 9; ++t) { float d = v9[t] - mean; var = fmaf(d, d, var); }
        float inv = 1.f / (sqrtf(var * (1.f / 8.f)) + 1e-10f);
        float o9[9];
#pragma unroll
        for (int t = 0; t < 9; ++t) o9[t] = (v9[t] - mean) * inv * sstd[t];
        float* o = sarr + ((size_t)b * HW_ + (size_t)row * W_ + pxl) * 12;
        *(float4*)(o)     = make_float4(o9[0], o9[1], o9[2], o9[3]);
        *(float4*)(o + 4) = make_float4(o9[4], o9[5], o9[6], o9[7]);
        *(float4*)(o + 8) = make_float4(o9[8], 0.f, 0.f, 0.f);
    }
}

// ------ cfk: reduce gap partials + SE MLP + FilterNorm -> cf (B,C,12 padded) ------
__global__ __launch_bounds__(256) void cfk(const float* __restrict__ gp,
    const float* __restrict__ cw1, const float* __restrict__ cb1,
    const float* __restrict__ cw2, const float* __restrict__ cb2,
    const float* __restrict__ cstd, float* __restrict__ cf) {
    const int tid = threadIdx.x;
    const int b = tid >> 6, c = tid & 63;
    __shared__ float gsm[B_][C_];
    __shared__ float hsm[B_][MID_];
    {
        const float4* p4 = (const float4*)(gp + ((size_t)b * C_ + c) * NPB_);
        float s = 0.f;
#pragma unroll 8
        for (int i = 0; i < NPB_ / 4; ++i) { float4 v = p4[i]; s += (v.x + v.y) + (v.z + v.w); }
        gsm[b][c] = s * (1.f / HW_);
    }
    __syncthreads();
    if (tid < B_ * MID_) {
        int b2 = tid / MID_, m = tid % MID_;
        float a = cb1[m];
        for (int cc = 0; cc < C_; ++cc) a = fmaf(gsm[b2][cc], cw1[m * C_ + cc], a);
        hsm[b2][m] = fmaxf(a, 0.f);
    }
    __syncthreads();
    float v[9];
    float mean = 0.f;
#pragma unroll
    for (int t = 0; t < 9; ++t) {
        int o = c * 9 + t;
        float a = cb2[o];
#pragma unroll
        for (int m = 0; m < MID_; ++m) a = fmaf(hsm[b][m], cw2[o * MID_ + m], a);
        v[t] = a;
        mean += a;
    }
    mean *= (1.f / 9.f);
    float var = 0.f;
#pragma unroll
    for (int t = 0; t < 9; ++t) { float d = v[t] - mean; var += d * d; }
    float inv = 1.f / (sqrtf(var * (1.f / 8.f)) + 1e-10f);
    float* o12 = cf + ((size_t)b * C_ + c) * 12;
#pragma unroll
    for (int t = 0; t < 9; ++t) o12[t] = (v[t] - mean) * inv * cstd[c * 9 + t];
    o12[9] = 0.f; o12[10] = 0.f; o12[11] = 0.f;
}

// ---------- apply: channel-parallel 3x3 dynamic filter (r20 structure, frozen) ----------
// block = 64x4 px tile, 8 channels; 1 px/thread; grid (W/64, H/4, B*8) = 8192.
template<bool RELU, bool RESID, bool INH, bool OUTH>
__global__ __launch_bounds__(256) void apply_kernel(const void* __restrict__ in,
    const float* __restrict__ sarr, const float* __restrict__ cf,
    const float* __restrict__ resid, void* __restrict__ out) {
    const int lane = threadIdx.x & 63, wv = threadIdx.x >> 6;
    const int col = blockIdx.x * 64 + lane;
    const int row = blockIdx.y * 4 + wv;
    const int z = blockIdx.z;
    const int b = z >> 3;
    const int c0 = (z & 7) * 8;
    const int pix = row * W_ + col;

    float s0[9];
    int off9[9];
    {
        const float* sp = sarr + ((size_t)b * HW_ + pix) * 12;
        float4 a = *(const float4*)(sp);
        float4 b4 = *(const float4*)(sp + 4);
        float4 c4 = *(const float4*)(sp + 8);
        s0[0] = a.x; s0[1] = a.y; s0[2] = a.z; s0[3] = a.w;
        s0[4] = b4.x; s0[5] = b4.y; s0[6] = b4.z; s0[7] = b4.w;
        s0[8] = c4.x;
#pragma unroll
        for (int dr = -1; dr <= 1; ++dr)
#pragma unroll
            for (int dc = -1; dc <= 1; ++dc) {
                const int t = (dr + 1) * 3 + (dc + 1);
                const bool ok = (row + dr >= 0) && (row + dr < H_) &&
                                (col + dc >= 0) && (col + dc < W_);
                off9[t] = ok ? (pix + dr * W_ + dc) : pix;
                if (!ok) s0[t] = 0.f;
            }
    }

    const size_t cbase = ((size_t)b * C_ + c0) * HW_;
    const float* inF = (const float*)in + cbase;
    const _Float16* inH = (const _Float16*)in + cbase;
    const float* cfb = cf + ((size_t)b * C_ + c0) * 12;
    const float* rb  = RESID ? ((const float*)resid + cbase + pix) : nullptr;
    float* outF = (float*)out + cbase + pix;
    _Float16* outH = (_Float16*)out + cbase + pix;

    float m0[9], m1[9], m2[9], m3[9];
    float rv0 = 0.f, rv1 = 0.f, rv2 = 0.f, rv3 = 0.f;

#define LD9(M, RV, cc) do {                                                  \
        if constexpr (INH) {                                                 \
            const _Float16* p_ = inH + (size_t)(cc) * HW_;                   \
            _Pragma("unroll")                                                \
            for (int t_ = 0; t_ < 9; ++t_) M[t_] = (float)p_[off9[t_]];      \
        } else {                                                             \
            const float* p_ = inF + (size_t)(cc) * HW_;                      \
            _Pragma("unroll")                                                \
            for (int t_ = 0; t_ < 9; ++t_) M[t_] = p_[off9[t_]];             \
        }                                                                    \
        if (RESID) RV = rb[(size_t)(cc) * HW_];                              \
    } while (0)

#define CP9(M, RV, cc) do {                                                  \
        const float* cfc_ = cfb + (size_t)(cc) * 12;                         \
        float acc_ = 0.f;                                                    \
        _Pragma("unroll")                                                    \
        for (int t_ = 0; t_ < 9; ++t_)                                       \
            acc_ = fmaf(M[t_] * s0[t_], cfc_[t_], acc_);                     \
        float o_ = RELU ? fmaxf(acc_, 0.f) : acc_;                           \
        if (RESID) o_ += RV;                                                 \
        if constexpr (OUTH) outH[(size_t)(cc) * HW_] = (_Float16)o_;         \
        else                outF[(size_t)(cc) * HW_] = o_;                   \
    } while (0)

    // depth-4 rotation over 8 channels
    LD9(m0, rv0, 0); LD9(m1, rv1, 1); LD9(m2, rv2, 2); LD9(m3, rv3, 3);
    CP9(m0, rv0, 0); LD9(m0, rv0, 4);
    CP9(m1, rv1, 1); LD9(m1, rv1, 5);
    CP9(m2, rv2, 2); LD9(m2, rv2, 6);
    CP9(m3, rv3, 3); LD9(m3, rv3, 7);
    CP9(m0, rv0, 4); CP9(m1, rv1, 5); CP9(m2, rv2, 6); CP9(m3, rv3, 7);
#undef LD9
#undef CP9
}

extern "C" void kernel_launch(void* const* d_in, const int* in_sizes, int n_in,
                              void* d_out, int out_size, void* d_ws, size_t ws_size,
                              hipStream_t stream) {
    const float* x     = (const float*)d_in[0];
    const float* sw1   = (const float*)d_in[1];
    const float* sb1   = (const float*)d_in[2];
    const float* sstd1 = (const float*)d_in[3];
    const float* cw1_1 = (const float*)d_in[4];
    const float* cb1_1 = (const float*)d_in[5];
    const float* cw2_1 = (const float*)d_in[6];
    const float* cb2_1 = (const float*)d_in[7];
    const float* cstd1 = (const float*)d_in[8];
    const float* sw2   = (const float*)d_in[9];
    const float* sb2   = (const float*)d_in[10];
    const float* sstd2 = (const float*)d_in[11];
    const float* cw1_2 = (const float*)d_in[12];
    const float* cb1_2 = (const float*)d_in[13];
    const float* cw2_2 = (const float*)d_in[14];
    const float* cb2_2 = (const float*)d_in[15];
    const float* cstd2 = (const float*)d_in[16];
    float* outp = (float*)d_out;

    const size_t n_out1 = (size_t)B_ * C_ * HW_;     // 16,777,216 (fp16)
    const size_t n_s    = (size_t)B_ * HW_ * 12;     // 3,145,728 (pixel-major)
    const size_t n_cf   = (size_t)B_ * C_ * 12;      // 3,072 (padded)
    const size_t n_gp   = (size_t)B_ * C_ * NPB_;    // 65,536
    const size_t need = n_out1 * sizeof(_Float16)
                      + (2 * n_s + 2 * n_cf + 2 * n_gp) * sizeof(float);
    if (ws_size < need) return;

    _Float16* out1h = (_Float16*)d_ws;
    float* s1  = (float*)((char*)d_ws + n_out1 * sizeof(_Float16));
    float* s2  = s1 + n_s;
    float* cf1 = s2 + n_s;
    float* cf2 = cf1 + n_cf;
    float* gp1 = cf2 + n_cf;
    float* gp2 = gp1 + n_gp;

    dim3 gprep(H_, B_);                     // 1024 blocks
    dim3 gapply(W_ / 64, H_ / 4, B_ * 8);   // 8192 blocks, 8 ch each

    // pass 1
    prep_kernel<false><<<gprep, 256, 0, stream>>>(x, sw1, sb1, sstd1, s1, gp1);
    cfk<<<1, 256, 0, stream>>>(gp1, cw1_1, cb1_1, cw2_1, cb2_1, cstd1, cf1);
    apply_kernel<true, false, false, true><<<gapply, 256, 0, stream>>>(
        x, s1, cf1, nullptr, out1h);
    // pass 2
    prep_kernel<true><<<gprep, 256, 0, stream>>>(out1h, sw2, sb2, sstd2, s2, gp2);
    cfk<<<1, 256, 0, stream>>>(gp2, cw1_2, cb1_2, cw2_2, cb2_2, cstd2, cf2);
    apply_kernel<false, true, true, false><<<gapply, 256, 0, stream>>>(
        out1h, s2, cf2, x, outp);
}

// Round 23
// 140.034 us; speedup vs baseline: 2.7484x; 2.7484x over previous
//
#include <hip/hip_runtime.h>

#define B_ 4
#define C_ 64
#define H_ 256
#define W_ 256
#define HW_ (H_*W_)
#define MID_ 12
#define NPB_ 256   // gap partial slots per image (= one per row)

typedef _Float16 h4 __attribute__((ext_vector_type(4)));

__device__ __forceinline__ float wave_reduce64(float v) {
#pragma unroll
    for (int off = 32; off; off >>= 1) v += __shfl_xor(v, off, 64);
    return v;
}

// FilterNorm over 9 taps (float4 over 4 px); writes PIXEL-MAJOR [px][12]
__device__ __forceinline__ void fnorm4_store_pm(const float4* t9,
    const float* __restrict__ sstd, float* sp /* = sarr + (b*HW+pix)*12 */) {
    float4 mean = make_float4(0, 0, 0, 0);
#pragma unroll
    for (int t = 0; t < 9; ++t) {
        mean.x += t9[t].x; mean.y += t9[t].y; mean.z += t9[t].z; mean.w += t9[t].w;
    }
    mean.x *= (1.f/9.f); mean.y *= (1.f/9.f); mean.z *= (1.f/9.f); mean.w *= (1.f/9.f);
    float4 var = make_float4(0, 0, 0, 0);
#pragma unroll
    for (int t = 0; t < 9; ++t) {
        float dx = t9[t].x - mean.x, dy = t9[t].y - mean.y;
        float dz = t9[t].z - mean.z, dw = t9[t].w - mean.w;
        var.x = fmaf(dx, dx, var.x); var.y = fmaf(dy, dy, var.y);
        var.z = fmaf(dz, dz, var.z); var.w = fmaf(dw, dw, var.w);
    }
    const float inv[4] = {
        1.f / (sqrtf(var.x * (1.f/8.f)) + 1e-10f),
        1.f / (sqrtf(var.y * (1.f/8.f)) + 1e-10f),
        1.f / (sqrtf(var.z * (1.f/8.f)) + 1e-10f),
        1.f / (sqrtf(var.w * (1.f/8.f)) + 1e-10f)};
    const float mn[4] = {mean.x, mean.y, mean.z, mean.w};
#pragma unroll
    for (int j = 0; j < 4; ++j) {
        float v9[9];
#pragma unroll
        for (int t = 0; t < 9; ++t) {
            float raw = (j == 0) ? t9[t].x : (j == 1) ? t9[t].y : (j == 2) ? t9[t].z : t9[t].w;
            v9[t] = (raw - mn[j]) * inv[j] * sstd[t];
        }
        float* o = sp + j * 12;
        *(float4*)(o)     = make_float4(v9[0], v9[1], v9[2], v9[3]);
        *(float4*)(o + 4) = make_float4(v9[4], v9[5], v9[6], v9[7]);
        *(float4*)(o + 8) = make_float4(v9[8], 0.f, 0.f, 0.f);
    }
}

// ---------------- prep: read in once -> s (pixel-major) + gap partials ----------------
// block = 1 row, 4 waves x 16 channels; lane = 4 px. grid (H, B). (r20 structure)
template<bool HALF>
__global__ __launch_bounds__(256) void prep_kernel(const void* __restrict__ xin,
    const float* __restrict__ sw, const float* __restrict__ sb,
    const float* __restrict__ sstd, float* __restrict__ sarr, float* __restrict__ gp) {
    const int lane = threadIdx.x & 63, wv = threadIdx.x >> 6;
    const int row = blockIdx.x;
    const int b = blockIdx.y;
    const int c0 = wv * 16;
    const int pix = row * W_ + lane * 4;
    __shared__ float4 stl[3][9][64];

    float4 st[9];
#pragma unroll
    for (int t = 0; t < 9; ++t) st[t] = make_float4(0, 0, 0, 0);

    const size_t base = (size_t)b * C_ * HW_ + pix;
    const float* xbF = (const float*)xin + base;
    const _Float16* xbH = (const _Float16*)xin + base;

#define LOAD4(DST, CC) do {                                                   \
        if constexpr (HALF) {                                                 \
            h4 v_ = *(const h4*)(xbH + (size_t)(CC) * HW_);                   \
            DST = make_float4((float)v_[0], (float)v_[1],                     \
                              (float)v_[2], (float)v_[3]);                    \
        } else {                                                              \
            DST = *(const float4*)(xbF + (size_t)(CC) * HW_);                 \
        }                                                                     \
    } while (0)

#define PREP_COMP(BUF, CC) do {                                               \
        _Pragma("unroll")                                                     \
        for (int i_ = 0; i_ < 4; ++i_) {                                      \
            const int c_ = (CC) + i_;                                         \
            float4 v_ = BUF[i_];                                              \
            _Pragma("unroll")                                                 \
            for (int t_ = 0; t_ < 9; ++t_) {                                  \
                const float wt_ = sw[t_ * C_ + c_];                           \
                st[t_].x = fmaf(v_.x, wt_, st[t_].x);                         \
                st[t_].y = fmaf(v_.y, wt_, st[t_].y);                         \
                st[t_].z = fmaf(v_.z, wt_, st[t_].z);                         \
                st[t_].w = fmaf(v_.w, wt_, st[t_].w);                         \
            }                                                                 \
            float g_ = wave_reduce64(((v_.x + v_.y) + (v_.z + v_.w)));        \
            if (lane == 0) gp[((size_t)b * C_ + c_) * NPB_ + blockIdx.x] = g_; \
        }                                                                     \
    } while (0)

    float4 vA[4], vB[4];
#pragma unroll
    for (int i = 0; i < 4; ++i) LOAD4(vA[i], c0 + i);
#pragma unroll
    for (int k = 0; k < 16; k += 8) {
#pragma unroll
        for (int i = 0; i < 4; ++i) LOAD4(vB[i], c0 + k + 4 + i);
        PREP_COMP(vA, c0 + k);
        if (k + 8 < 16) {
#pragma unroll
            for (int i = 0; i < 4; ++i) LOAD4(vA[i], c0 + k + 8 + i);
        }
        PREP_COMP(vB, c0 + k + 4);
    }
#undef LOAD4
#undef PREP_COMP

    if (wv) {
#pragma unroll
        for (int t = 0; t < 9; ++t) stl[wv - 1][t][lane] = st[t];
    }
    __syncthreads();
    if (wv == 0) {
#pragma unroll
        for (int t = 0; t < 9; ++t) {
            float bb = sb[t];
#pragma unroll
            for (int j = 0; j < 3; ++j) {
                float4 o = stl[j][t][lane];
                st[t].x += o.x; st[t].y += o.y; st[t].z += o.z; st[t].w += o.w;
            }
            st[t].x += bb; st[t].y += bb; st[t].z += bb; st[t].w += bb;
        }
        fnorm4_store_pm(st, sstd, sarr + ((size_t)b * HW_ + pix) * 12);
    }
}

// ------ cfk: reduce gap partials + SE MLP + FilterNorm -> cf (B,C,12 padded) ------
__global__ __launch_bounds__(256) void cfk(const float* __restrict__ gp,
    const float* __restrict__ cw1, const float* __restrict__ cb1,
    const float* __restrict__ cw2, const float* __restrict__ cb2,
    const float* __restrict__ cstd, float* __restrict__ cf) {
    const int tid = threadIdx.x;
    const int b = tid >> 6, c = tid & 63;
    __shared__ float gsm[B_][C_];
    __shared__ float hsm[B_][MID_];
    {
        const float4* p4 = (const float4*)(gp + ((size_t)b * C_ + c) * NPB_);
        float s = 0.f;
#pragma unroll 8
        for (int i = 0; i < NPB_ / 4; ++i) { float4 v = p4[i]; s += (v.x + v.y) + (v.z + v.w); }
        gsm[b][c] = s * (1.f / HW_);
    }
    __syncthreads();
    if (tid < B_ * MID_) {
        int b2 = tid / MID_, m = tid % MID_;
        float a = cb1[m];
        for (int cc = 0; cc < C_; ++cc) a = fmaf(gsm[b2][cc], cw1[m * C_ + cc], a);
        hsm[b2][m] = fmaxf(a, 0.f);
    }
    __syncthreads();
    float v[9];
    float mean = 0.f;
#pragma unroll
    for (int t = 0; t < 9; ++t) {
        int o = c * 9 + t;
        float a = cb2[o];
#pragma unroll
        for (int m = 0; m < MID_; ++m) a = fmaf(hsm[b][m], cw2[o * MID_ + m], a);
        v[t] = a;
        mean += a;
    }
    mean *= (1.f / 9.f);
    float var = 0.f;
#pragma unroll
    for (int t = 0; t < 9; ++t) { float d = v[t] - mean; var += d * d; }
    float inv = 1.f / (sqrtf(var * (1.f / 8.f)) + 1e-10f);
    float* o12 = cf + ((size_t)b * C_ + c) * 12;
#pragma unroll
    for (int t = 0; t < 9; ++t) o12[t] = (v[t] - mean) * inv * cstd[c * 9 + t];
    o12[9] = 0.f; o12[10] = 0.f; o12[11] = 0.f;
}

// ---------- apply: channel-parallel 3x3 dynamic filter, depth-4 pipeline ----------
// block = 64x4 px tile, 8 channels; 1 px/thread; grid (W/64, H/4, B*8) = 8192.
// s loaded as 3 float4 (pixel-major); edge masks folded into s0/off9.
template<bool RELU, bool RESID, bool INH, bool OUTH>
__global__ __launch_bounds__(256) void apply_kernel(const void* __restrict__ in,
    const float* __restrict__ sarr, const float* __restrict__ cf,
    const float* __restrict__ resid, void* __restrict__ out) {
    const int lane = threadIdx.x & 63, wv = threadIdx.x >> 6;
    const int col = blockIdx.x * 64 + lane;
    const int row = blockIdx.y * 4 + wv;
    const int z = blockIdx.z;
    const int b = z >> 3;
    const int c0 = (z & 7) * 8;
    const int pix = row * W_ + col;

    // s taps at my pixel (3 contiguous float4s); fold ALL edge masking here
    float s0[9];
    int off9[9];
    {
        const float* sp = sarr + ((size_t)b * HW_ + pix) * 12;
        float4 a = *(const float4*)(sp);
        float4 b4 = *(const float4*)(sp + 4);
        float4 c4 = *(const float4*)(sp + 8);
        s0[0] = a.x; s0[1] = a.y; s0[2] = a.z; s0[3] = a.w;
        s0[4] = b4.x; s0[5] = b4.y; s0[6] = b4.z; s0[7] = b4.w;
        s0[8] = c4.x;
#pragma unroll
        for (int dr = -1; dr <= 1; ++dr)
#pragma unroll
            for (int dc = -1; dc <= 1; ++dc) {
                const int t = (dr + 1) * 3 + (dc + 1);
                const bool ok = (row + dr >= 0) && (row + dr < H_) &&
                                (col + dc >= 0) && (col + dc < W_);
                off9[t] = ok ? (pix + dr * W_ + dc) : pix;
                if (!ok) s0[t] = 0.f;
            }
    }

    const size_t cbase = ((size_t)b * C_ + c0) * HW_;
    const float* inF = (const float*)in + cbase;
    const _Float16* inH = (const _Float16*)in + cbase;
    const float* cfb = cf + ((size_t)b * C_ + c0) * 12;
    const float* rb  = RESID ? ((const float*)resid + cbase + pix) : nullptr;
    float* outF = (float*)out + cbase + pix;
    _Float16* outH = (_Float16*)out + cbase + pix;

    float m0[9], m1[9], m2[9], m3[9];
    float rv0 = 0.f, rv1 = 0.f, rv2 = 0.f, rv3 = 0.f;

#define LD9(M, RV, cc) do {                                                  \
        if constexpr (INH) {                                                 \
            const _Float16* p_ = inH + (size_t)(cc) * HW_;                   \
            _Pragma("unroll")                                                \
            for (int t_ = 0; t_ < 9; ++t_) M[t_] = (float)p_[off9[t_]];      \
        } else {                                                             \
            const float* p_ = inF + (size_t)(cc) * HW_;                      \
            _Pragma("unroll")                                                \
            for (int t_ = 0; t_ < 9; ++t_) M[t_] = p_[off9[t_]];             \
        }                                                                    \
        if (RESID) RV = rb[(size_t)(cc) * HW_];                              \
    } while (0)

#define CP9(M, RV, cc) do {                                                  \
        const float* cfc_ = cfb + (size_t)(cc) * 12;                         \
        float acc_ = 0.f;                                                    \
        _Pragma("unroll")                                                    \
        for (int t_ = 0; t_ < 9; ++t_)                                       \
            acc_ = fmaf(M[t_] * s0[t_], cfc_[t_], acc_);                     \
        float o_ = RELU ? fmaxf(acc_, 0.f) : acc_;                           \
        if (RESID) o_ += RV;                                                 \
        if constexpr (OUTH) outH[(size_t)(cc) * HW_] = (_Float16)o_;         \
        else                outF[(size_t)(cc) * HW_] = o_;                   \
    } while (0)

    // depth-4 rotation over 8 channels
    LD9(m0, rv0, 0); LD9(m1, rv1, 1); LD9(m2, rv2, 2); LD9(m3, rv3, 3);
    CP9(m0, rv0, 0); LD9(m0, rv0, 4);
    CP9(m1, rv1, 1); LD9(m1, rv1, 5);
    CP9(m2, rv2, 2); LD9(m2, rv2, 6);
    CP9(m3, rv3, 3); LD9(m3, rv3, 7);
    CP9(m0, rv0, 4); CP9(m1, rv1, 5); CP9(m2, rv2, 6); CP9(m3, rv3, 7);
#undef LD9
#undef CP9
}

extern "C" void kernel_launch(void* const* d_in, const int* in_sizes, int n_in,
                              void* d_out, int out_size, void* d_ws, size_t ws_size,
                              hipStream_t stream) {
    const float* x     = (const float*)d_in[0];
    const float* sw1   = (const float*)d_in[1];
    const float* sb1   = (const float*)d_in[2];
    const float* sstd1 = (const float*)d_in[3];
    const float* cw1_1 = (const float*)d_in[4];
    const float* cb1_1 = (const float*)d_in[5];
    const float* cw2_1 = (const float*)d_in[6];
    const float* cb2_1 = (const float*)d_in[7];
    const float* cstd1 = (const float*)d_in[8];
    const float* sw2   = (const float*)d_in[9];
    const float* sb2   = (const float*)d_in[10];
    const float* sstd2 = (const float*)d_in[11];
    const float* cw1_2 = (const float*)d_in[12];
    const float* cb1_2 = (const float*)d_in[13];
    const float* cw2_2 = (const float*)d_in[14];
    const float* cb2_2 = (const float*)d_in[15];
    const float* cstd2 = (const float*)d_in[16];
    float* outp = (float*)d_out;

    const size_t n_out1 = (size_t)B_ * C_ * HW_;     // 16,777,216 (fp16)
    const size_t n_s    = (size_t)B_ * HW_ * 12;     // 3,145,728 (pixel-major)
    const size_t n_cf   = (size_t)B_ * C_ * 12;      // 3,072 (padded)
    const size_t n_gp   = (size_t)B_ * C_ * NPB_;    // 65,536
    const size_t need = n_out1 * sizeof(_Float16)
                      + (2 * n_s + 2 * n_cf + 2 * n_gp) * sizeof(float);
    if (ws_size < need) return;

    _Float16* out1h = (_Float16*)d_ws;
    float* s1  = (float*)((char*)d_ws + n_out1 * sizeof(_Float16));
    float* s2  = s1 + n_s;
    float* cf1 = s2 + n_s;
    float* cf2 = cf1 + n_cf;
    float* gp1 = cf2 + n_cf;
    float* gp2 = gp1 + n_gp;

    dim3 gprep(H_, B_);                     // 1024 blocks
    dim3 gapply(W_ / 64, H_ / 4, B_ * 8);   // 8192 blocks, 8 ch each

    // pass 1
    prep_kernel<false><<<gprep, 256, 0, stream>>>(x, sw1, sb1, sstd1, s1, gp1);
    cfk<<<1, 256, 0, stream>>>(gp1, cw1_1, cb1_1, cw2_1, cb2_1, cstd1, cf1);
    apply_kernel<true, false, false, true><<<gapply, 256, 0, stream>>>(
        x, s1, cf1, nullptr, out1h);
    // pass 2
    prep_kernel<true><<<gprep, 256, 0, stream>>>(out1h, sw2, sb2, sstd2, s2, gp2);
    cfk<<<1, 256, 0, stream>>>(gp2, cw1_2, cb1_2, cw2_2, cb2_2, cstd2, cf2);
    apply_kernel<false, true, true, false><<<gapply, 256, 0, stream>>>(
        out1h, s2, cf2, x, outp);
}